// Round 14
// baseline (3795.057 us; speedup 1.0000x reference)
//
#include <hip/hip_runtime.h>

typedef __attribute__((ext_vector_type(8))) short s8v;
typedef __attribute__((ext_vector_type(8))) __bf16 bf8v;
typedef __attribute__((ext_vector_type(4))) float f32x4;
typedef unsigned long long ULL;

#define DEVINL __device__ __forceinline__

DEVINL unsigned short f2bf(float f) {
    unsigned int x = __float_as_uint(f);
    unsigned int r = (x + 0x7FFFu + ((x >> 16) & 1u)) >> 16;
    return (unsigned short)r;
}

DEVINL f32x4 mfma16(s8v a, s8v b, f32x4 c) {
    return __builtin_amdgcn_mfma_f32_16x16x32_bf16(
        __builtin_bit_cast(bf8v, a), __builtin_bit_cast(bf8v, b), c, 0, 0, 0);
}

typedef const __attribute__((address_space(1))) unsigned int gu32;
typedef __attribute__((address_space(3))) unsigned int lu32;
DEVINL void gload16(const void* g, unsigned int lds_off) {
    __builtin_amdgcn_global_load_lds((gu32*)g, (lu32*)(size_t)lds_off, 16, 0, 0);
}

#define AGENT __HIP_MEMORY_SCOPE_AGENT

// ---------------- workspace layout (bytes) ----------------
#define WS_CTR   0                        // [2 layers][2 dirs][4 producers] seq words, 64B apart
#define WS_HBUF  4096                     // [2 layers][2 dirs][2 buf][32][512] bf16 = 262144
#define WS_WIH   266240                   // bf16 [2][2][1536][1024] = 12582912
#define WS_WHH   (WS_WIH + 12582912)      // bf16 [2][2][1536][512]  = 6291456
#define WS_EMB   (WS_WHH + 6291456)       // bf16 [2048][1024] = 4194304
#define WS_ST1   (WS_EMB + 4194304)       // bf16 [2048][1024] = 4194304
#define WS_GX    (WS_ST1 + 4194304)       // f32  [2048][3072] = 25165824

// ---------------- fused prep: conv attention + both bf16 cvts + flag zeroing --------
__global__ __launch_bounds__(256) void k_prep(const float* __restrict__ inp,
                                              const float* __restrict__ conv_w,
                                              const float* __restrict__ conv_b,
                                              float* __restrict__ wts_out,
                                              unsigned short* __restrict__ emb,
                                              const float* __restrict__ wih,
                                              unsigned short* __restrict__ wih16,
                                              const float* __restrict__ whh,
                                              unsigned short* __restrict__ whh16,
                                              unsigned int* __restrict__ flagz) {
    const int bid = blockIdx.x, tid = threadIdx.x;
    if (bid >= 2048) {
        const float* src;
        unsigned short* dst;
        int i0;
        if (bid < 5120) { src = wih; dst = wih16; i0 = ((bid - 2048) * 256 + tid) * 8; }
        else            { src = whh; dst = whh16; i0 = ((bid - 5120) * 256 + tid) * 8; }
        f32x4 a = *(const f32x4*)(src + i0);
        f32x4 b = *(const f32x4*)(src + i0 + 4);
        s8v o;
        o[0] = (short)f2bf(a[0]); o[1] = (short)f2bf(a[1]);
        o[2] = (short)f2bf(a[2]); o[3] = (short)f2bf(a[3]);
        o[4] = (short)f2bf(b[0]); o[5] = (short)f2bf(b[1]);
        o[6] = (short)f2bf(b[2]); o[7] = (short)f2bf(b[3]);
        *(s8v*)(dst + i0) = o;
        return;
    }
    const int bs = bid;
    if (bs == 0) {
        for (int i = tid; i < 1024; i += 256)
            __hip_atomic_store(&flagz[i], 0u, __ATOMIC_RELAXED, AGENT);
    }
    __shared__ float xs[32][260];
    __shared__ float sc[4][32];
    __shared__ float wts[4][32];
    const float* x = inp + (size_t)bs * 8192;
    {
        int p = tid >> 3, i0 = (tid & 7) * 32;
        const float* src = x + p * 256 + i0;
        float* dst = &xs[p][i0];
#pragma unroll
        for (int j = 0; j < 32; j += 4) *(f32x4*)(dst + j) = *(const f32x4*)(src + j);
    }
    __syncthreads();
    {
        int p = tid >> 3, o = tid & 7;
        float s0 = 0, s1 = 0, s2 = 0, s3 = 0;
        const float* xp = &xs[p][o * 32];
#pragma unroll
        for (int j = 0; j < 32; j += 4) {
            f32x4 v  = *(const f32x4*)(xp + j);
            f32x4 w0 = *(const f32x4*)(conv_w + o * 32 + j);
            f32x4 w1 = *(const f32x4*)(conv_w + 256 + o * 32 + j);
            f32x4 w2 = *(const f32x4*)(conv_w + 512 + o * 32 + j);
            f32x4 w3 = *(const f32x4*)(conv_w + 768 + o * 32 + j);
#pragma unroll
            for (int q = 0; q < 4; ++q) {
                s0 += v[q] * w0[q]; s1 += v[q] * w1[q];
                s2 += v[q] * w2[q]; s3 += v[q] * w3[q];
            }
        }
#pragma unroll
        for (int d = 4; d; d >>= 1) {
            s0 += __shfl_down(s0, d, 8); s1 += __shfl_down(s1, d, 8);
            s2 += __shfl_down(s2, d, 8); s3 += __shfl_down(s3, d, 8);
        }
        if (o == 0) {
            sc[0][p] = s0 + conv_b[0]; sc[1][p] = s1 + conv_b[1];
            sc[2][p] = s2 + conv_b[2]; sc[3][p] = s3 + conv_b[3];
        }
    }
    __syncthreads();
    if (tid < 4) {
        float mx = -1e30f;
        for (int p = 0; p < 32; ++p) mx = fmaxf(mx, sc[tid][p]);
        float sm = 0.f;
        for (int p = 0; p < 32; ++p) { float e = __expf(sc[tid][p] - mx); wts[tid][p] = e; sm += e; }
        float inv = 1.f / sm;
        for (int p = 0; p < 32; ++p) wts[tid][p] *= inv;
    }
    __syncthreads();
    if (tid < 128) wts_out[(size_t)bs * 128 + tid] = wts[tid >> 5][tid & 31];
    {
        float a0 = 0, a1 = 0, a2 = 0, a3 = 0;
#pragma unroll 8
        for (int p = 0; p < 32; ++p) {
            float v = xs[p][tid];
            a0 += wts[0][p] * v; a1 += wts[1][p] * v;
            a2 += wts[2][p] * v; a3 += wts[3][p] * v;
        }
        unsigned short* e = emb + (size_t)bs * 1024;
        e[tid] = f2bf(a0); e[256 + tid] = f2bf(a1);
        e[512 + tid] = f2bf(a2); e[768 + tid] = f2bf(a3);
    }
}

// ---------------- bf16 GEMM 128x64 tile (768 blocks): C = A*B^T + bias (+bias2 r/z) --
__global__ __launch_bounds__(256, 2) void k_gemm(const unsigned short* __restrict__ A,
                                                 const unsigned short* __restrict__ B,
                                                 const float* __restrict__ bias,
                                                 const float* __restrict__ bias2,
                                                 float* __restrict__ C,
                                                 int M, int N, int K) {
    const int bm = blockIdx.y * 128, bn = blockIdx.x * 64;
    const int tid = threadIdx.x, w = tid >> 6, l = tid & 63;
    const int wr = w >> 1, wc = w & 1;
    const int lr = l & 15, lq = l >> 4;

    __shared__ __align__(1024) unsigned short As[8192]; // [128][64] linear
    __shared__ __align__(1024) unsigned short Bs[4096]; // [64][64] linear
    const unsigned int AsOff = (unsigned int)(size_t)(void*)As;
    const unsigned int BsOff = (unsigned int)(size_t)(void*)Bs;

    f32x4 acc[4][2] = {};
    const int srow = tid >> 3;
    const int scol = ((tid & 7) ^ (srow & 7)) * 8;
    const unsigned int wbase = w * 1024;

    for (int k0 = 0; k0 < K; k0 += 64) {
        __syncthreads();
#pragma unroll
        for (int j = 0; j < 4; ++j)
            gload16(A + (size_t)(bm + j * 32 + srow) * K + k0 + scol,
                    AsOff + j * 4096 + wbase);
#pragma unroll
        for (int j = 0; j < 2; ++j)
            gload16(B + (size_t)(bn + j * 32 + srow) * K + k0 + scol,
                    BsOff + j * 4096 + wbase);
        asm volatile("s_waitcnt vmcnt(0)" ::: "memory");
        __syncthreads();
#pragma unroll
        for (int kk = 0; kk < 2; ++kk) {
            s8v af[4], bf_[2];
#pragma unroll
            for (int mt = 0; mt < 4; ++mt) {
                const int row = wr * 64 + mt * 16 + lr;
                const int qg = kk * 4 + lq;
                af[mt] = *(const s8v*)((const char*)As + row * 128 +
                                       ((qg ^ (row & 7)) << 4));
            }
#pragma unroll
            for (int nt = 0; nt < 2; ++nt) {
                const int row = wc * 32 + nt * 16 + lr;
                const int qg = kk * 4 + lq;
                bf_[nt] = *(const s8v*)((const char*)Bs + row * 128 +
                                        ((qg ^ (row & 7)) << 4));
            }
#pragma unroll
            for (int mt = 0; mt < 4; ++mt)
#pragma unroll
                for (int nt = 0; nt < 2; ++nt)
                    acc[mt][nt] = mfma16(af[mt], bf_[nt], acc[mt][nt]);
        }
    }
#pragma unroll
    for (int mt = 0; mt < 4; ++mt)
#pragma unroll
        for (int nt = 0; nt < 2; ++nt)
#pragma unroll
            for (int r = 0; r < 4; ++r) {
                int row = bm + wr * 64 + mt * 16 + lq * 4 + r;
                int col = bn + wc * 32 + nt * 16 + lr;
                int gg = col >> 9;                 // 0..5 = r0,z0,n0,r1,z1,n1
                float b2 = (gg != 2 && gg != 5) ? bias2[col] : 0.f;
                C[(size_t)row * N + col] = acc[mt][nt][r] + bias[col] + b2;
            }
}

// ---------------- GRU scan (proven body; 4 producers/dir x 512 threads) -------------
// 8 blocks of 512: dir = blk>>2, jg = blk&3 owns h cols [jg*128, jg*128+128).
// Halved producer count: last-producer publish tail + 4-line flag discovery +
// 4-iteration staging, with per-wave body (16 cols, 192 weight VGPRs, MFMA, gates,
// publish) byte-identical to the proven 318-us version. t==0 skip retained.
__global__ __launch_bounds__(512, 1) void k_scan(const float* __restrict__ gx,   // [2048][3072]
                                                 const unsigned short* __restrict__ whh, // [2][1536][512]
                                                 const float* __restrict__ bhh,  // [2][1536]
                                                 unsigned short* __restrict__ hbuf, // [2 dir][2 buf][32][512]
                                                 unsigned int* __restrict__ flags,  // [2 dir][4] 64B apart
                                                 float* __restrict__ st32,
                                                 unsigned short* __restrict__ st16) {
    const int blk = blockIdx.x;
    const int dir = blk >> 2, jg = blk & 3;
    const int tid = threadIdx.x;
    const int w = tid >> 6, l = tid & 63;      // w in [0,8)
    const int lr = l & 15, lq = l >> 4;
    const int jb = jg * 128;
    const int mycol = jb + w * 16 + lr;

    __shared__ __align__(1024) unsigned short hs[16384]; // [32][512] bf16, XOR-swizzled

    // persistent B fragments: 3 gates x 16 k-tiles (192 VGPRs)
    s8v bf[3][16];
#pragma unroll
    for (int g = 0; g < 3; ++g) {
        const unsigned short* wr =
            whh + ((size_t)dir * 1536 + g * 512 + mycol) * 512 + lq * 8;
#pragma unroll
        for (int kt = 0; kt < 16; ++kt) bf[g][kt] = *(const s8v*)(wr + kt * 32);
    }
    const float bh_n = bhh[dir * 1536 + 1024 + mycol];   // n-gate bias (not foldable)

    unsigned short* hb0 = hbuf + (size_t)dir * 32768;
    unsigned int* fl = flags + dir * 128;          // 4 producers, 16-uint stride
    unsigned int* myflag = fl + jg * 16;

    float hp[2][4] = {{0.f, 0.f, 0.f, 0.f}, {0.f, 0.f, 0.f, 0.f}};

    for (int t = 0; t < 64; ++t) {
        const int s = dir ? (63 - t) : t;
        // ---- prefetch gx (independent of h; issued pre-poll) ----
        float pg[3][2][4];
#pragma unroll
        for (int g = 0; g < 3; ++g)
#pragma unroll
            for (int bt = 0; bt < 2; ++bt)
#pragma unroll
                for (int r = 0; r < 4; ++r) {
                    const int b = bt * 16 + lq * 4 + r;
                    pg[g][bt][r] = gx[(size_t)(b * 64 + s) * 3072 + dir * 1536 +
                                      g * 512 + mycol];
                }
        f32x4 acc[3][2] = {};
        if (t > 0) {
            // ---- wave-0 poll of 4 producer seq words + barrier broadcast ----
            if (w == 0 && l < 4) {
                while (__hip_atomic_load(&fl[l * 16], __ATOMIC_RELAXED, AGENT) <
                       (unsigned)t)
                    __builtin_amdgcn_s_sleep(1);
            }
            __syncthreads();
            // ---- stage h_t into LDS (swizzled) via relaxed 8B atomic loads ----
            const unsigned short* hc = hb0 + (size_t)(t & 1) * 16384;
#pragma unroll
            for (int i = 0; i < 4; ++i) {
                const int c = tid + 512 * i;
                const int row = c >> 6, inb = (c & 63) * 16;
                const ULL* hq = (const ULL*)(hc + c * 8);
                ULL d0 = __hip_atomic_load(hq, __ATOMIC_RELAXED, AGENT);
                ULL d1 = __hip_atomic_load(hq + 1, __ATOMIC_RELAXED, AGENT);
                char* dst = (char*)hs + row * 1024 + (inb ^ ((row & 7) << 4));
                *(ULL*)dst = d0;
                *(ULL*)(dst + 8) = d1;
            }
            __syncthreads();
            // ---- MFMA: 3 gate-tiles x 2 batch-tiles, A-frag shared across gates ----
#pragma unroll
            for (int bt = 0; bt < 2; ++bt) {
                const int row = bt * 16 + lr;
                const int m = (row & 7) << 4;
#pragma unroll
                for (int kt = 0; kt < 16; ++kt) {
                    s8v a = *(const s8v*)((const char*)hs + row * 1024 +
                                          ((kt * 64 + lq * 16) ^ m));
                    acc[0][bt] = mfma16(a, bf[0][kt], acc[0][bt]);
                    acc[1][bt] = mfma16(a, bf[1][kt], acc[1][bt]);
                    acc[2][bt] = mfma16(a, bf[2][kt], acc[2][bt]);
                }
            }
        }
        // ---- gates fully in registers + publish h_{t+1} ----
        unsigned short* hnw = hb0 + (size_t)((t + 1) & 1) * 16384;
        float hnew[2][4];
#pragma unroll
        for (int bt = 0; bt < 2; ++bt)
#pragma unroll
            for (int r = 0; r < 4; ++r) {
                const int b = bt * 16 + lq * 4 + r;
                float r_ = __builtin_amdgcn_rcpf(
                    1.f + __expf(-(pg[0][bt][r] + acc[0][bt][r])));
                float z_ = __builtin_amdgcn_rcpf(
                    1.f + __expf(-(pg[1][bt][r] + acc[1][bt][r])));
                float q = pg[2][bt][r] + r_ * (acc[2][bt][r] + bh_n);
                q = fminf(fmaxf(q, -15.f), 15.f);
                float e = __expf(2.f * q);
                float n_ = (e - 1.f) * __builtin_amdgcn_rcpf(e + 1.f);
                float h = (1.f - z_) * n_ + z_ * hp[bt][r];
                hp[bt][r] = h;
                hnew[bt][r] = h;
                __hip_atomic_store(&hnw[b * 512 + mycol], f2bf(h), __ATOMIC_RELAXED,
                                   AGENT);
            }
        __syncthreads();  // vmcnt(0) drain for every wave -> publishes at LLC
        if (tid == 0 && t < 63)
            __hip_atomic_store(myflag, (unsigned)(t + 1), __ATOMIC_RELAXED, AGENT);
        // ---- states stores, off the signaling path ----
#pragma unroll
        for (int bt = 0; bt < 2; ++bt)
#pragma unroll
            for (int r = 0; r < 4; ++r) {
                const int b = bt * 16 + lq * 4 + r;
                const size_t so = (size_t)(b * 64 + s) * 1024 + dir * 512 + mycol;
                if (st32) st32[so] = hnew[bt][r];
                if (st16) st16[so] = f2bf(hnew[bt][r]);
            }
    }
}

// ---------------- finale ----------------
__global__ __launch_bounds__(256) void k_finale(const float* __restrict__ states,
                                                const float* __restrict__ conv2_w,
                                                const float* __restrict__ conv2_b,
                                                const float* __restrict__ demoip,
                                                const float* __restrict__ lin_w,
                                                const float* __restrict__ lin_b,
                                                float* __restrict__ out,
                                                float* __restrict__ context,
                                                float* __restrict__ alpha) {
    const int b = blockIdx.x, tid = threadIdx.x, w = tid >> 6, l = tid & 63;
    __shared__ float dots[64], al[64], ctx[1024], lg[2];
    const float* st = states + (size_t)b * 65536;
    for (int si = 0; si < 16; ++si) {
        int s = w * 16 + si;
        const float* row = st + s * 1024;
        float sum = 0.f;
        for (int i = l; i < 1024; i += 64) sum += row[i] * conv2_w[i];
#pragma unroll
        for (int m = 32; m; m >>= 1) sum += __shfl_xor(sum, m, 64);
        if (l == 0) dots[s] = sum + conv2_b[0];
    }
    __syncthreads();
    if (w == 0) {
        float v = dots[l];
        float mx = v;
#pragma unroll
        for (int m = 32; m; m >>= 1) mx = fmaxf(mx, __shfl_xor(mx, m, 64));
        float e = __expf(v - mx);
        float sm = e;
#pragma unroll
        for (int m = 32; m; m >>= 1) sm += __shfl_xor(sm, m, 64);
        float a = e / sm;
        al[l] = a;
        alpha[b * 64 + l] = a;
    }
    __syncthreads();
    for (int h = tid; h < 1024; h += 256) {
        float c = 0.f;
#pragma unroll 8
        for (int s = 0; s < 64; ++s) c += al[s] * st[s * 1024 + h];
        ctx[h] = c;
        context[b * 1024 + h] = c;
    }
    __syncthreads();
    if (w < 2) {
        const float* lw = lin_w + w * 1027;
        float sum = 0.f;
        for (int i = l; i < 1024; i += 64) sum += ctx[i] * lw[i];
#pragma unroll
        for (int m = 32; m; m >>= 1) sum += __shfl_xor(sum, m, 64);
        if (l == 0) {
            sum += lw[1024] * demoip[b * 3] + lw[1025] * demoip[b * 3 + 1] +
                   lw[1026] * demoip[b * 3 + 2] + lin_b[w];
            lg[w] = sum;
        }
    }
    __syncthreads();
    if (tid == 0) {
        float m = fmaxf(lg[0], lg[1]);
        float e0 = __expf(lg[0] - m), e1 = __expf(lg[1] - m);
        float inv = 1.f / (e0 + e1);
        out[b * 2 + 0] = e0 * inv;
        out[b * 2 + 1] = e1 * inv;
    }
}

extern "C" void kernel_launch(void* const* d_in, const int* in_sizes, int n_in,
                              void* d_out, int out_size, void* d_ws, size_t ws_size,
                              hipStream_t stream) {
    const float* inputs  = (const float*)d_in[0];
    const float* demoip  = (const float*)d_in[1];
    const float* conv_w  = (const float*)d_in[2];
    const float* conv_b  = (const float*)d_in[3];
    const float* conv2_w = (const float*)d_in[4];
    const float* conv2_b = (const float*)d_in[5];
    const float* wih     = (const float*)d_in[6];
    const float* whh     = (const float*)d_in[7];
    const float* bih     = (const float*)d_in[8];
    const float* bhh     = (const float*)d_in[9];
    const float* lin_w   = (const float*)d_in[10];
    const float* lin_b   = (const float*)d_in[11];

    char* ws = (char*)d_ws;
    unsigned int* ctrs    = (unsigned int*)(ws + WS_CTR);
    unsigned short* hbuf  = (unsigned short*)(ws + WS_HBUF);
    unsigned short* wih16 = (unsigned short*)(ws + WS_WIH);
    unsigned short* whh16 = (unsigned short*)(ws + WS_WHH);
    unsigned short* emb16 = (unsigned short*)(ws + WS_EMB);
    unsigned short* st116 = (unsigned short*)(ws + WS_ST1);
    float* gxbuf          = (float*)(ws + WS_GX);

    float* out_out    = (float*)d_out;
    float* wts_out    = out_out + 64;
    float* states_out = out_out + 262208;
    float* ctx_out    = out_out + 2359360;
    float* alpha_out  = out_out + 2392128;

    // fused prep: conv + wih cvt + whh cvt + flag zeroing (no memset launch)
    k_prep<<<6656, 256, 0, stream>>>(inputs, conv_w, conv_b, wts_out, emb16,
                                     wih, wih16, whh, whh16, ctrs);
    // layer 1 (bhh r/z folded into GEMM bias)
    k_gemm<<<dim3(48, 16), 256, 0, stream>>>(emb16, wih16, bih, bhh, gxbuf,
                                             2048, 3072, 1024);
    k_scan<<<8, 512, 0, stream>>>(gxbuf, whh16, bhh, hbuf, ctrs, nullptr, st116);
    // layer 2
    k_gemm<<<dim3(48, 16), 256, 0, stream>>>(st116, wih16 + 3145728, bih + 3072,
                                             bhh + 3072, gxbuf, 2048, 3072, 1024);
    k_scan<<<8, 512, 0, stream>>>(gxbuf, whh16 + 1572864, bhh + 3072, hbuf + 65536,
                                  ctrs + 256, states_out, nullptr);
    k_finale<<<32, 256, 0, stream>>>(states_out, conv2_w, conv2_b, demoip, lin_w, lin_b,
                                     out_out, ctx_out, alpha_out);
}

// Round 15
// 798.208 us; speedup vs baseline: 4.7545x; 4.7545x over previous
//
#include <hip/hip_runtime.h>

typedef __attribute__((ext_vector_type(8))) short s8v;
typedef __attribute__((ext_vector_type(8))) __bf16 bf8v;
typedef __attribute__((ext_vector_type(4))) float f32x4;
typedef unsigned long long ULL;

#define DEVINL __device__ __forceinline__

DEVINL unsigned short f2bf(float f) {
    unsigned int x = __float_as_uint(f);
    unsigned int r = (x + 0x7FFFu + ((x >> 16) & 1u)) >> 16;
    return (unsigned short)r;
}

DEVINL f32x4 mfma16(s8v a, s8v b, f32x4 c) {
    return __builtin_amdgcn_mfma_f32_16x16x32_bf16(
        __builtin_bit_cast(bf8v, a), __builtin_bit_cast(bf8v, b), c, 0, 0, 0);
}

typedef const __attribute__((address_space(1))) unsigned int gu32;
typedef __attribute__((address_space(3))) unsigned int lu32;
DEVINL void gload16(const void* g, unsigned int lds_off) {
    __builtin_amdgcn_global_load_lds((gu32*)g, (lu32*)(size_t)lds_off, 16, 0, 0);
}

#define AGENT __HIP_MEMORY_SCOPE_AGENT

// ---------------- workspace layout (bytes) ----------------
#define WS_CTR   0                        // [2 layers][2 dirs][8 producers] seq words, 64B apart (4 KB)
#define WS_HBUF  4096                     // [2 layers][2 dirs][2 buf][32][512] bf16 = 262144
#define WS_WIH   266240                   // bf16 [2][2][1536][1024] = 12582912
#define WS_WHH   (WS_WIH + 12582912)      // bf16 [2][2][1536][512]  = 6291456
#define WS_EMB   (WS_WHH + 6291456)       // bf16 [2048][1024] = 4194304
#define WS_ST1   (WS_EMB + 4194304)       // bf16 [2048][1024] = 4194304
#define WS_GX    (WS_ST1 + 4194304)       // f32  [2048][3072] = 25165824

// ---------------- fused prep: conv attention + both bf16 cvts + flag zeroing --------
// grid 6656: [0,2048) conv ; [2048,5120) cvt wih ; [5120,6656) cvt whh.
// conv block 0 additionally zeroes the flag region (runs before any scan; resets
// the monotonic flags on every graph replay).
__global__ __launch_bounds__(256) void k_prep(const float* __restrict__ inp,
                                              const float* __restrict__ conv_w,
                                              const float* __restrict__ conv_b,
                                              float* __restrict__ wts_out,
                                              unsigned short* __restrict__ emb,
                                              const float* __restrict__ wih,
                                              unsigned short* __restrict__ wih16,
                                              const float* __restrict__ whh,
                                              unsigned short* __restrict__ whh16,
                                              unsigned int* __restrict__ flagz) {
    const int bid = blockIdx.x, tid = threadIdx.x;
    if (bid >= 2048) {
        const float* src;
        unsigned short* dst;
        int i0;
        if (bid < 5120) { src = wih; dst = wih16; i0 = ((bid - 2048) * 256 + tid) * 8; }
        else            { src = whh; dst = whh16; i0 = ((bid - 5120) * 256 + tid) * 8; }
        f32x4 a = *(const f32x4*)(src + i0);
        f32x4 b = *(const f32x4*)(src + i0 + 4);
        s8v o;
        o[0] = (short)f2bf(a[0]); o[1] = (short)f2bf(a[1]);
        o[2] = (short)f2bf(a[2]); o[3] = (short)f2bf(a[3]);
        o[4] = (short)f2bf(b[0]); o[5] = (short)f2bf(b[1]);
        o[6] = (short)f2bf(b[2]); o[7] = (short)f2bf(b[3]);
        *(s8v*)(dst + i0) = o;
        return;
    }
    const int bs = bid;
    if (bs == 0) {
        for (int i = tid; i < 1024; i += 256)
            __hip_atomic_store(&flagz[i], 0u, __ATOMIC_RELAXED, AGENT);
    }
    __shared__ float xs[32][260];
    __shared__ float sc[4][32];
    __shared__ float wts[4][32];
    const float* x = inp + (size_t)bs * 8192;
    {
        int p = tid >> 3, i0 = (tid & 7) * 32;
        const float* src = x + p * 256 + i0;
        float* dst = &xs[p][i0];
#pragma unroll
        for (int j = 0; j < 32; j += 4) *(f32x4*)(dst + j) = *(const f32x4*)(src + j);
    }
    __syncthreads();
    {
        int p = tid >> 3, o = tid & 7;
        float s0 = 0, s1 = 0, s2 = 0, s3 = 0;
        const float* xp = &xs[p][o * 32];
#pragma unroll
        for (int j = 0; j < 32; j += 4) {
            f32x4 v  = *(const f32x4*)(xp + j);
            f32x4 w0 = *(const f32x4*)(conv_w + o * 32 + j);
            f32x4 w1 = *(const f32x4*)(conv_w + 256 + o * 32 + j);
            f32x4 w2 = *(const f32x4*)(conv_w + 512 + o * 32 + j);
            f32x4 w3 = *(const f32x4*)(conv_w + 768 + o * 32 + j);
#pragma unroll
            for (int q = 0; q < 4; ++q) {
                s0 += v[q] * w0[q]; s1 += v[q] * w1[q];
                s2 += v[q] * w2[q]; s3 += v[q] * w3[q];
            }
        }
#pragma unroll
        for (int d = 4; d; d >>= 1) {
            s0 += __shfl_down(s0, d, 8); s1 += __shfl_down(s1, d, 8);
            s2 += __shfl_down(s2, d, 8); s3 += __shfl_down(s3, d, 8);
        }
        if (o == 0) {
            sc[0][p] = s0 + conv_b[0]; sc[1][p] = s1 + conv_b[1];
            sc[2][p] = s2 + conv_b[2]; sc[3][p] = s3 + conv_b[3];
        }
    }
    __syncthreads();
    if (tid < 4) {
        float mx = -1e30f;
        for (int p = 0; p < 32; ++p) mx = fmaxf(mx, sc[tid][p]);
        float sm = 0.f;
        for (int p = 0; p < 32; ++p) { float e = __expf(sc[tid][p] - mx); wts[tid][p] = e; sm += e; }
        float inv = 1.f / sm;
        for (int p = 0; p < 32; ++p) wts[tid][p] *= inv;
    }
    __syncthreads();
    if (tid < 128) wts_out[(size_t)bs * 128 + tid] = wts[tid >> 5][tid & 31];
    {
        float a0 = 0, a1 = 0, a2 = 0, a3 = 0;
#pragma unroll 8
        for (int p = 0; p < 32; ++p) {
            float v = xs[p][tid];
            a0 += wts[0][p] * v; a1 += wts[1][p] * v;
            a2 += wts[2][p] * v; a3 += wts[3][p] * v;
        }
        unsigned short* e = emb + (size_t)bs * 1024;
        e[tid] = f2bf(a0); e[256 + tid] = f2bf(a1);
        e[512 + tid] = f2bf(a2); e[768 + tid] = f2bf(a3);
    }
}

// ---------------- bf16 GEMM 128x64 tile (768 blocks): C = A*B^T + bias (+bias2 r/z) --
__global__ __launch_bounds__(256, 2) void k_gemm(const unsigned short* __restrict__ A,
                                                 const unsigned short* __restrict__ B,
                                                 const float* __restrict__ bias,
                                                 const float* __restrict__ bias2,
                                                 float* __restrict__ C,
                                                 int M, int N, int K) {
    const int bm = blockIdx.y * 128, bn = blockIdx.x * 64;
    const int tid = threadIdx.x, w = tid >> 6, l = tid & 63;
    const int wr = w >> 1, wc = w & 1;
    const int lr = l & 15, lq = l >> 4;

    __shared__ __align__(1024) unsigned short As[8192]; // [128][64] linear
    __shared__ __align__(1024) unsigned short Bs[4096]; // [64][64] linear
    const unsigned int AsOff = (unsigned int)(size_t)(void*)As;
    const unsigned int BsOff = (unsigned int)(size_t)(void*)Bs;

    f32x4 acc[4][2] = {};
    const int srow = tid >> 3;
    const int scol = ((tid & 7) ^ (srow & 7)) * 8;
    const unsigned int wbase = w * 1024;

    for (int k0 = 0; k0 < K; k0 += 64) {
        __syncthreads();
#pragma unroll
        for (int j = 0; j < 4; ++j)
            gload16(A + (size_t)(bm + j * 32 + srow) * K + k0 + scol,
                    AsOff + j * 4096 + wbase);
#pragma unroll
        for (int j = 0; j < 2; ++j)
            gload16(B + (size_t)(bn + j * 32 + srow) * K + k0 + scol,
                    BsOff + j * 4096 + wbase);
        asm volatile("s_waitcnt vmcnt(0)" ::: "memory");
        __syncthreads();
#pragma unroll
        for (int kk = 0; kk < 2; ++kk) {
            s8v af[4], bf_[2];
#pragma unroll
            for (int mt = 0; mt < 4; ++mt) {
                const int row = wr * 64 + mt * 16 + lr;
                const int qg = kk * 4 + lq;
                af[mt] = *(const s8v*)((const char*)As + row * 128 +
                                       ((qg ^ (row & 7)) << 4));
            }
#pragma unroll
            for (int nt = 0; nt < 2; ++nt) {
                const int row = wc * 32 + nt * 16 + lr;
                const int qg = kk * 4 + lq;
                bf_[nt] = *(const s8v*)((const char*)Bs + row * 128 +
                                        ((qg ^ (row & 7)) << 4));
            }
#pragma unroll
            for (int mt = 0; mt < 4; ++mt)
#pragma unroll
                for (int nt = 0; nt < 2; ++nt)
                    acc[mt][nt] = mfma16(af[mt], bf_[nt], acc[mt][nt]);
        }
    }
#pragma unroll
    for (int mt = 0; mt < 4; ++mt)
#pragma unroll
        for (int nt = 0; nt < 2; ++nt)
#pragma unroll
            for (int r = 0; r < 4; ++r) {
                int row = bm + wr * 64 + mt * 16 + lq * 4 + r;
                int col = bn + wc * 32 + nt * 16 + lr;
                int gg = col >> 9;                 // 0..5 = r0,z0,n0,r1,z1,n1
                float b2 = (gg != 2 && gg != 5) ? bias2[col] : 0.f;
                C[(size_t)row * N + col] = acc[mt][nt][r] + bias[col] + b2;
            }
}

// ---------------- GRU scan (proven 318-us body; t==0 skip -> no hbuf zeroing) -------
// 16 blocks of 256: dir = blk>>3, jg = blk&7 owns h cols [jg*64, jg*64+64).
// Per step: prefetch gx -> wave-0 poll of 8 per-producer seq words + barrier
// broadcast -> stage h via relaxed 8B atomic loads into XOR-swizzled LDS -> barrier
// -> MFMA (3 gates x 2 batch-tiles) -> gates in regs (r/z biases folded into gx by
// k_gemm) -> 2B write-through publish -> barrier (vmcnt drain) -> relaxed flag
// store -> states stores off the signaling path.  t==0: h_0 = 0 -> skip
// poll/stage/MFMA (acc = 0), so hbuf needs no initialization across replays.
__global__ __launch_bounds__(256, 1) void k_scan(const float* __restrict__ gx,   // [2048][3072]
                                                 const unsigned short* __restrict__ whh, // [2][1536][512]
                                                 const float* __restrict__ bhh,  // [2][1536]
                                                 unsigned short* __restrict__ hbuf, // [2 dir][2 buf][32][512]
                                                 unsigned int* __restrict__ flags,  // [2 dir][8] 64B apart
                                                 float* __restrict__ st32,
                                                 unsigned short* __restrict__ st16) {
    const int blk = blockIdx.x;
    const int dir = blk >> 3, jg = blk & 7;
    const int tid = threadIdx.x;
    const int w = tid >> 6, l = tid & 63;
    const int lr = l & 15, lq = l >> 4;
    const int jb = jg * 64;
    const int mycol = jb + w * 16 + lr;

    __shared__ __align__(1024) unsigned short hs[16384]; // [32][512] bf16, XOR-swizzled

    // persistent B fragments: 3 gates x 16 k-tiles (192 VGPRs)
    s8v bf[3][16];
#pragma unroll
    for (int g = 0; g < 3; ++g) {
        const unsigned short* wr =
            whh + ((size_t)dir * 1536 + g * 512 + mycol) * 512 + lq * 8;
#pragma unroll
        for (int kt = 0; kt < 16; ++kt) bf[g][kt] = *(const s8v*)(wr + kt * 32);
    }
    const float bh_n = bhh[dir * 1536 + 1024 + mycol];   // n-gate bias (not foldable)

    unsigned short* hb0 = hbuf + (size_t)dir * 32768;
    unsigned int* fl = flags + dir * 128;          // 8 producers, 16-uint stride
    unsigned int* myflag = fl + jg * 16;

    float hp[2][4] = {{0.f, 0.f, 0.f, 0.f}, {0.f, 0.f, 0.f, 0.f}};

    for (int t = 0; t < 64; ++t) {
        const int s = dir ? (63 - t) : t;
        // ---- prefetch gx (independent of h; issued pre-poll) ----
        float pg[3][2][4];
#pragma unroll
        for (int g = 0; g < 3; ++g)
#pragma unroll
            for (int bt = 0; bt < 2; ++bt)
#pragma unroll
                for (int r = 0; r < 4; ++r) {
                    const int b = bt * 16 + lq * 4 + r;
                    pg[g][bt][r] = gx[(size_t)(b * 64 + s) * 3072 + dir * 1536 +
                                      g * 512 + mycol];
                }
        f32x4 acc[3][2] = {};
        if (t > 0) {
            // ---- wave-0 poll of 8 producer seq words + barrier broadcast ----
            if (w == 0 && l < 8) {
                while (__hip_atomic_load(&fl[l * 16], __ATOMIC_RELAXED, AGENT) <
                       (unsigned)t)
                    __builtin_amdgcn_s_sleep(1);
            }
            __syncthreads();
            // ---- stage h_t into LDS (swizzled) via relaxed 8B atomic loads ----
            const unsigned short* hc = hb0 + (size_t)(t & 1) * 16384;
#pragma unroll
            for (int i = 0; i < 8; ++i) {
                const int c = tid + 256 * i;
                const int row = c >> 6, inb = (c & 63) * 16;
                const ULL* hq = (const ULL*)(hc + c * 8);
                ULL d0 = __hip_atomic_load(hq, __ATOMIC_RELAXED, AGENT);
                ULL d1 = __hip_atomic_load(hq + 1, __ATOMIC_RELAXED, AGENT);
                char* dst = (char*)hs + row * 1024 + (inb ^ ((row & 7) << 4));
                *(ULL*)dst = d0;
                *(ULL*)(dst + 8) = d1;
            }
            __syncthreads();
            // ---- MFMA: 3 gate-tiles x 2 batch-tiles, A-frag shared across gates ----
#pragma unroll
            for (int bt = 0; bt < 2; ++bt) {
                const int row = bt * 16 + lr;
                const int m = (row & 7) << 4;
#pragma unroll
                for (int kt = 0; kt < 16; ++kt) {
                    s8v a = *(const s8v*)((const char*)hs + row * 1024 +
                                          ((kt * 64 + lq * 16) ^ m));
                    acc[0][bt] = mfma16(a, bf[0][kt], acc[0][bt]);
                    acc[1][bt] = mfma16(a, bf[1][kt], acc[1][bt]);
                    acc[2][bt] = mfma16(a, bf[2][kt], acc[2][bt]);
                }
            }
        }
        // ---- gates fully in registers + publish h_{t+1} ----
        unsigned short* hnw = hb0 + (size_t)((t + 1) & 1) * 16384;
        float hnew[2][4];
#pragma unroll
        for (int bt = 0; bt < 2; ++bt)
#pragma unroll
            for (int r = 0; r < 4; ++r) {
                const int b = bt * 16 + lq * 4 + r;
                float r_ = __builtin_amdgcn_rcpf(
                    1.f + __expf(-(pg[0][bt][r] + acc[0][bt][r])));
                float z_ = __builtin_amdgcn_rcpf(
                    1.f + __expf(-(pg[1][bt][r] + acc[1][bt][r])));
                float q = pg[2][bt][r] + r_ * (acc[2][bt][r] + bh_n);
                q = fminf(fmaxf(q, -15.f), 15.f);
                float e = __expf(2.f * q);
                float n_ = (e - 1.f) * __builtin_amdgcn_rcpf(e + 1.f);
                float h = (1.f - z_) * n_ + z_ * hp[bt][r];
                hp[bt][r] = h;
                hnew[bt][r] = h;
                __hip_atomic_store(&hnw[b * 512 + mycol], f2bf(h), __ATOMIC_RELAXED,
                                   AGENT);
            }
        __syncthreads();  // vmcnt(0) drain for every wave -> publishes at LLC
        if (tid == 0 && t < 63)
            __hip_atomic_store(myflag, (unsigned)(t + 1), __ATOMIC_RELAXED, AGENT);
        // ---- states stores, off the signaling path ----
#pragma unroll
        for (int bt = 0; bt < 2; ++bt)
#pragma unroll
            for (int r = 0; r < 4; ++r) {
                const int b = bt * 16 + lq * 4 + r;
                const size_t so = (size_t)(b * 64 + s) * 1024 + dir * 512 + mycol;
                if (st32) st32[so] = hnew[bt][r];
                if (st16) st16[so] = f2bf(hnew[bt][r]);
            }
    }
}

// ---------------- finale ----------------
__global__ __launch_bounds__(256) void k_finale(const float* __restrict__ states,
                                                const float* __restrict__ conv2_w,
                                                const float* __restrict__ conv2_b,
                                                const float* __restrict__ demoip,
                                                const float* __restrict__ lin_w,
                                                const float* __restrict__ lin_b,
                                                float* __restrict__ out,
                                                float* __restrict__ context,
                                                float* __restrict__ alpha) {
    const int b = blockIdx.x, tid = threadIdx.x, w = tid >> 6, l = tid & 63;
    __shared__ float dots[64], al[64], ctx[1024], lg[2];
    const float* st = states + (size_t)b * 65536;
    for (int si = 0; si < 16; ++si) {
        int s = w * 16 + si;
        const float* row = st + s * 1024;
        float sum = 0.f;
        for (int i = l; i < 1024; i += 64) sum += row[i] * conv2_w[i];
#pragma unroll
        for (int m = 32; m; m >>= 1) sum += __shfl_xor(sum, m, 64);
        if (l == 0) dots[s] = sum + conv2_b[0];
    }
    __syncthreads();
    if (w == 0) {
        float v = dots[l];
        float mx = v;
#pragma unroll
        for (int m = 32; m; m >>= 1) mx = fmaxf(mx, __shfl_xor(mx, m, 64));
        float e = __expf(v - mx);
        float sm = e;
#pragma unroll
        for (int m = 32; m; m >>= 1) sm += __shfl_xor(sm, m, 64);
        float a = e / sm;
        al[l] = a;
        alpha[b * 64 + l] = a;
    }
    __syncthreads();
    for (int h = tid; h < 1024; h += 256) {
        float c = 0.f;
#pragma unroll 8
        for (int s = 0; s < 64; ++s) c += al[s] * st[s * 1024 + h];
        ctx[h] = c;
        context[b * 1024 + h] = c;
    }
    __syncthreads();
    if (w < 2) {
        const float* lw = lin_w + w * 1027;
        float sum = 0.f;
        for (int i = l; i < 1024; i += 64) sum += ctx[i] * lw[i];
#pragma unroll
        for (int m = 32; m; m >>= 1) sum += __shfl_xor(sum, m, 64);
        if (l == 0) {
            sum += lw[1024] * demoip[b * 3] + lw[1025] * demoip[b * 3 + 1] +
                   lw[1026] * demoip[b * 3 + 2] + lin_b[w];
            lg[w] = sum;
        }
    }
    __syncthreads();
    if (tid == 0) {
        float m = fmaxf(lg[0], lg[1]);
        float e0 = __expf(lg[0] - m), e1 = __expf(lg[1] - m);
        float inv = 1.f / (e0 + e1);
        out[b * 2 + 0] = e0 * inv;
        out[b * 2 + 1] = e1 * inv;
    }
}

extern "C" void kernel_launch(void* const* d_in, const int* in_sizes, int n_in,
                              void* d_out, int out_size, void* d_ws, size_t ws_size,
                              hipStream_t stream) {
    const float* inputs  = (const float*)d_in[0];
    const float* demoip  = (const float*)d_in[1];
    const float* conv_w  = (const float*)d_in[2];
    const float* conv_b  = (const float*)d_in[3];
    const float* conv2_w = (const float*)d_in[4];
    const float* conv2_b = (const float*)d_in[5];
    const float* wih     = (const float*)d_in[6];
    const float* whh     = (const float*)d_in[7];
    const float* bih     = (const float*)d_in[8];
    const float* bhh     = (const float*)d_in[9];
    const float* lin_w   = (const float*)d_in[10];
    const float* lin_b   = (const float*)d_in[11];

    char* ws = (char*)d_ws;
    unsigned int* ctrs    = (unsigned int*)(ws + WS_CTR);
    unsigned short* hbuf  = (unsigned short*)(ws + WS_HBUF);
    unsigned short* wih16 = (unsigned short*)(ws + WS_WIH);
    unsigned short* whh16 = (unsigned short*)(ws + WS_WHH);
    unsigned short* emb16 = (unsigned short*)(ws + WS_EMB);
    unsigned short* st116 = (unsigned short*)(ws + WS_ST1);
    float* gxbuf          = (float*)(ws + WS_GX);

    float* out_out    = (float*)d_out;
    float* wts_out    = out_out + 64;
    float* states_out = out_out + 262208;
    float* ctx_out    = out_out + 2359360;
    float* alpha_out  = out_out + 2392128;

    // fused prep: conv + wih cvt + whh cvt + flag zeroing (no memset launch)
    k_prep<<<6656, 256, 0, stream>>>(inputs, conv_w, conv_b, wts_out, emb16,
                                     wih, wih16, whh, whh16, ctrs);
    // layer 1 (bhh r/z folded into GEMM bias)
    k_gemm<<<dim3(48, 16), 256, 0, stream>>>(emb16, wih16, bih, bhh, gxbuf,
                                             2048, 3072, 1024);
    k_scan<<<16, 256, 0, stream>>>(gxbuf, whh16, bhh, hbuf, ctrs, nullptr, st116);
    // layer 2
    k_gemm<<<dim3(48, 16), 256, 0, stream>>>(st116, wih16 + 3145728, bih + 3072,
                                             bhh + 3072, gxbuf, 2048, 3072, 1024);
    k_scan<<<16, 256, 0, stream>>>(gxbuf, whh16 + 1572864, bhh + 3072, hbuf + 65536,
                                   ctrs + 256, states_out, nullptr);
    k_finale<<<32, 256, 0, stream>>>(states_out, conv2_w, conv2_b, demoip, lin_w, lin_b,
                                     out_out, ctx_out, alpha_out);
}